// Round 2
// baseline (291.634 us; speedup 1.0000x reference)
//
#include <hip/hip_runtime.h>
#include <hip/hip_bf16.h>

#define N_IMG 4
#define C_CH 256
#define H_DIM 64
#define W_DIM 64
#define HW 4096
#define NCLASS 20
#define NHEADS 4
#define HD 64   // channels per head

typedef __attribute__((ext_vector_type(8))) short short8;
typedef __attribute__((ext_vector_type(4))) float f32x4;

__device__ __forceinline__ ushort f2bf(float f) {
    unsigned u = __float_as_uint(f);
    u += 0x7FFFu + ((u >> 16) & 1u);   // RNE
    return (ushort)(u >> 16);
}

// ---------------------------------------------------------------------------
__global__ void k_init(unsigned* mmax) {
    if (threadIdx.x < N_IMG) mmax[threadIdx.x] = 0u;
}

// mask pre-normalization + per-image max; 256 threads: 4 c-chunks x 64 w
__global__ __launch_bounds__(256) void k_mask_m(const float* __restrict__ feats,
                         const float* __restrict__ wgap,
                         const int* __restrict__ label,
                         float* __restrict__ mask, unsigned* __restrict__ mmax) {
    int b = blockIdx.x;            // N*H = 256
    int n = b >> 6, h = b & 63;
    int t = threadIdx.x;
    int w = t & 63, cq = t >> 6;
    __shared__ float wrow[C_CH];
    __shared__ float part[4][64];
    int lab = label[n];
    wrow[t] = wgap[lab * C_CH + t];
    __syncthreads();
    const float* fp = feats + ((size_t)(n * C_CH + cq * 64)) * HW + h * W_DIM + w;
    float acc = 0.f;
    for (int c = 0; c < 64; c++) acc += fp[(size_t)c * HW] * wrow[cq * 64 + c];
    part[cq][w] = acc;
    __syncthreads();
    if (cq == 0) {
        float m = fmaxf(part[0][w] + part[1][w] + part[2][w] + part[3][w], 0.f);
        mask[n * HW + h * W_DIM + w] = m;
        for (int off = 32; off; off >>= 1) m = fmaxf(m, __shfl_down(m, off, 64));
        if (w == 0) atomicMax(&mmax[n], __float_as_uint(m));
    }
}

__global__ void k_mask_norm(float* __restrict__ mask, const unsigned* __restrict__ mmax) {
    int i = blockIdx.x * 256 + threadIdx.x;
    if (i < N_IMG * HW) {
        int n = i / HW;
        float mx = fmaxf(__uint_as_float(mmax[n]), 1.0f);
        mask[i] = mask[i] / mx;
    }
}

// per-(n,c) plane sum for GAP on feats
__global__ void k_plane_sum(const float* __restrict__ x, float* __restrict__ S) {
    int nc = blockIdx.x;
    const float* p = x + (size_t)nc * HW;
    float s = 0.f;
    for (int i = threadIdx.x; i < HW; i += 256) s += p[i];
    __shared__ float red[4];
    for (int off = 32; off; off >>= 1) s += __shfl_down(s, off, 64);
    int wid = threadIdx.x >> 6;
    if ((threadIdx.x & 63) == 0) red[wid] = s;
    __syncthreads();
    if (threadIdx.x == 0) S[nc] = red[0] + red[1] + red[2] + red[3];
}

__global__ void k_pred(const float* __restrict__ S, const float* __restrict__ wg,
                       float* __restrict__ out) {
    int idx = threadIdx.x;
    if (idx < N_IMG * NCLASS) {
        int n = idx / NCLASS, k = idx % NCLASS;
        float s = 0.f;
        for (int c = 0; c < C_CH; c++) s += wg[k * C_CH + c] * S[n * C_CH + c];
        out[idx] = s * (1.0f / HW);
    }
}

// ---------------------------------------------------------------------------
// infusion attention scores (5x5, dil 3): 16-wave structure, writes normalized
// att to global. att[((a*25+k)*N + n)*HW + h*64 + w]
__global__ __launch_bounds__(1024) void k_att_inf(
    const float* __restrict__ patch_t,   // Q (im2col side)
    const float* __restrict__ center_t,  // K (center side)
    float* __restrict__ att) {
    int b = blockIdx.x;                 // N*H = 256
    int n = b >> 6, h = b & 63;
    int t = threadIdx.x;
    int w = t & 63;
    int a = (t >> 6) & 3;
    int cq = t >> 8;                    // channel quarter
    __shared__ float att_s[4][25][64];  // 25.6 KB
    for (int i = t; i < 4 * 25 * 64; i += 1024) ((float*)att_s)[i] = 0.f;
    __syncthreads();

    int off[25];
#pragma unroll
    for (int k = 0; k < 25; k++) {
        int y = h + (k / 5 - 2) * 3, x = w + (k % 5 - 2) * 3;
        off[k] = (y >= 0 && y < 64 && x >= 0 && x < 64) ? y * 64 + x : -1;
    }
    float s[25];
#pragma unroll
    for (int k = 0; k < 25; k++) s[k] = 0.f;
    const float* cp = center_t + ((size_t)(n * C_CH + a * HD + cq * 16)) * HW + h * W_DIM + w;
    const float* pp = patch_t + ((size_t)(n * C_CH + a * HD + cq * 16)) * HW;
    for (int c = 0; c < 16; c++) {
        float cen = cp[(size_t)c * HW];
        const float* pc = pp + (size_t)c * HW;
#pragma unroll
        for (int k = 0; k < 25; k++) {
            float pv = (off[k] >= 0) ? pc[off[k]] : 0.f;
            s[k] += pv * cen;
        }
    }
#pragma unroll
    for (int k = 0; k < 25; k++) atomicAdd(&att_s[a][k][w], s[k]);
    __syncthreads();
    if (cq == 0) {
        float v[25];
        float mx = -1e30f;
#pragma unroll
        for (int k = 0; k < 25; k++) { v[k] = att_s[a][k][w]; mx = fmaxf(mx, v[k]); }
        float sum = 0.f;
#pragma unroll
        for (int k = 0; k < 25; k++) { v[k] = __expf(v[k] - mx); sum += v[k]; }
        float inv = 1.0f / sum;
#pragma unroll
        for (int k = 0; k < 25; k++)
            att[((size_t)(a * 25 + k) * N_IMG + n) * HW + h * 64 + w] = v[k] * inv;
    }
}

// W_a[n,y,x] = sum_k att[a,k,(y-dy_k, x-dx_k)] (scatter form of the GAP sum)
__global__ __launch_bounds__(256) void k_scatter_w(const float* __restrict__ att,
                                                   float* __restrict__ W) {
    int b = blockIdx.x;   // n*64 + y
    int n = b >> 6, y = b & 63;
    int t = threadIdx.x;
    int x = t & 63, a = t >> 6;
    float s = 0.f;
#pragma unroll
    for (int k = 0; k < 25; k++) {
        int sy = y - (k / 5 - 2) * 3, sx = x - (k % 5 - 2) * 3;
        if (sy >= 0 && sy < 64 && sx >= 0 && sx < 64)
            s += att[((size_t)(a * 25 + k) * N_IMG + n) * HW + sy * 64 + sx];
    }
    W[((size_t)a * N_IMG + n) * HW + y * 64 + x] = s;
}

// S_r[n,c] = sum_px feats[n,c,px] * W[a(c),n,px]  (weighted plane sum, f32x4)
__global__ __launch_bounds__(256) void k_wsum(const float* __restrict__ V,
                                              const float* __restrict__ W,
                                              float* __restrict__ S) {
    int nc = blockIdx.x;               // n*256 + c
    int n = nc >> 8, c = nc & 255;
    int a = c >> 6;
    const f32x4* p4 = (const f32x4*)(V + (size_t)nc * HW);
    const f32x4* w4 = (const f32x4*)(W + ((size_t)a * N_IMG + n) * HW);
    f32x4 a4 = (f32x4){0.f, 0.f, 0.f, 0.f};
    for (int i = threadIdx.x; i < HW / 4; i += 256) {
        f32x4 u = p4[i], v = w4[i];
        a4 += u * v;
    }
    float s = a4[0] + a4[1] + a4[2] + a4[3];
    __shared__ float red[4];
    for (int off = 32; off; off >>= 1) s += __shfl_down(s, off, 64);
    int wid = threadIdx.x >> 6;
    if ((threadIdx.x & 63) == 0) red[wid] = s;
    __syncthreads();
    if (threadIdx.x == 0) S[nc] = red[0] + red[1] + red[2] + red[3];
}

// ---------------------------------------------------------------------------
// diffusion attention scores (3x3, dil 6), masked — 16-wave version
__global__ __launch_bounds__(1024) void k_att_dif(
    const float* __restrict__ patch_t,   // K
    const float* __restrict__ center_t,  // Q
    const float* __restrict__ mask, float* __restrict__ att) {
    int b = blockIdx.x;                 // N*H = 256
    int n = b >> 6, h = b & 63;
    int t = threadIdx.x;
    int w = t & 63;
    int a = (t >> 6) & 3;
    int cq = t >> 8;
    __shared__ float att_s[4][9][64];   // 9.2 KB
    for (int i = t; i < 4 * 9 * 64; i += 1024) ((float*)att_s)[i] = 0.f;
    __syncthreads();

    int off[9];
#pragma unroll
    for (int k = 0; k < 9; k++) {
        int y = h + (k / 3 - 1) * 6, x = w + (k % 3 - 1) * 6;
        off[k] = (y >= 0 && y < 64 && x >= 0 && x < 64) ? y * 64 + x : -1;
    }
    float s[9];
#pragma unroll
    for (int k = 0; k < 9; k++) s[k] = 0.f;
    const float* cp = center_t + ((size_t)(n * C_CH + a * HD + cq * 16)) * HW + h * W_DIM + w;
    const float* pp = patch_t + ((size_t)(n * C_CH + a * HD + cq * 16)) * HW;
    for (int c = 0; c < 16; c++) {
        float cen = cp[(size_t)c * HW];
        const float* pc = pp + (size_t)c * HW;
#pragma unroll
        for (int k = 0; k < 9; k++) {
            float pv = (off[k] >= 0) ? pc[off[k]] : 0.f;
            s[k] += pv * cen;
        }
    }
#pragma unroll
    for (int k = 0; k < 9; k++) atomicAdd(&att_s[a][k][w], s[k]);
    __syncthreads();
    if (cq == 0) {
        float v[9];
        float mx = -1e30f;
#pragma unroll
        for (int k = 0; k < 9; k++) { v[k] = att_s[a][k][w]; mx = fmaxf(mx, v[k]); }
        float sum = 0.f;
#pragma unroll
        for (int k = 0; k < 9; k++) { v[k] = __expf(v[k] - mx); sum += v[k]; }
        float mm = mask[n * HW + h * W_DIM + w] / sum;
#pragma unroll
        for (int k = 0; k < 9; k++)
            att[((size_t)(a * 9 + k) * N_IMG + n) * HW + h * W_DIM + w] = v[k] * mm;
    }
}

// ---------------------------------------------------------------------------
// Zero only the halo border of xinp [4][66][66][512] (interior is fully
// rewritten by k_prep_fused every launch). 260 segments of 512 ushorts per n.
__global__ __launch_bounds__(256) void k_zero_border(ushort* __restrict__ xinp) {
    int b = blockIdx.x;            // n*260 + seg
    int n = b / 260, seg = b % 260;
    size_t base;
    if (seg < 66)       base = ((size_t)(n * 66 + 0) * 66 + seg) * 512;
    else if (seg < 132) base = ((size_t)(n * 66 + 65) * 66 + (seg - 66)) * 512;
    else {
        int c = seg - 132;
        int r = 1 + (c >> 1), x = (c & 1) ? 65 : 0;
        base = ((size_t)(n * 66 + r) * 66 + x) * 512;
    }
    ((unsigned*)(xinp + base))[threadIdx.x] = 0u;   // 256 x 4B = 1024B = 512 ushorts
}

// ---------------------------------------------------------------------------
// FUSED conv-input prep: ic<256 -> feats*mask; ic>=256 -> diffusion gather,
// both packed to bf16 padded-NHWC xinp[4][66][66][512]. One block = (y, n, x-half).
__global__ __launch_bounds__(256) void k_prep_fused(
    const float* __restrict__ feats, const float* __restrict__ mask,
    const float* __restrict__ att, ushort* __restrict__ xinp) {
    int y = blockIdx.x, n = blockIdx.y, xh = blockIdx.z;
    int t = threadIdx.x;
    int xl = t & 31, cg = t >> 5;     // 8 c-groups
    int x = xh * 32 + xl;
    __shared__ ushort sx2[32][520];
    __shared__ float att_s[4][9][64];
    for (int idx = t; idx < 4 * 9 * 64; idx += 256) {
        int a = idx / 576, rem = idx % 576, k = rem >> 6, w = rem & 63;
        int sy = y - (k / 3 - 1) * 6;
        att_s[a][k][w] = (sy >= 0 && sy < 64)
            ? att[((size_t)(a * 9 + k) * N_IMG + n) * HW + sy * 64 + w] : 0.f;
    }
    float mval = mask[n * HW + y * 64 + x];
    __syncthreads();
    int sxo[9]; bool sxv[9];
#pragma unroll
    for (int k = 0; k < 9; k++) {
        int sy = y - (k / 3 - 1) * 6, sx = x - (k % 3 - 1) * 6;
        sxo[k] = sy * 64 + sx;
        sxv[k] = (sy >= 0 && sy < 64 && sx >= 0 && sx < 64);
    }
    for (int c8 = 0; c8 < 64; c8++) {
        int c = c8 * 8 + cg;
        float v;
        if (c < 256) {
            v = feats[((size_t)(n * C_CH + c)) * HW + y * 64 + x] * mval;
        } else {
            int cd = c - 256, a = cd >> 6;
            const float* vp = feats + ((size_t)(n * C_CH + cd)) * HW;
            v = 0.f;
#pragma unroll
            for (int k = 0; k < 9; k++) {
                if (sxv[k]) v += vp[sxo[k]] * att_s[a][k][(x - (k % 3 - 1) * 6)];
            }
        }
        sx2[xl][c] = f2bf(v);
    }
    __syncthreads();
    for (int xp = 0; xp < 32; xp++) {
        unsigned lo = sx2[xp][2 * t], hi = sx2[xp][2 * t + 1];
        unsigned* dst = (unsigned*)(xinp + ((size_t)(n * 66 + y + 1) * 66 + xh * 32 + xp + 1) * 512);
        dst[t] = lo | (hi << 16);
    }
}

// prep: conv_w [256][512][3][3] f32 -> wt2[16][256][9][32] bf16 (tap-contiguous per oc)
__global__ __launch_bounds__(256) void k_prep_w(const float* __restrict__ cw,
                                                ushort* __restrict__ wt2) {
    int idx = blockIdx.x * 256 + threadIdx.x;   // oc*512+ic
    int oc = idx >> 9, ic = idx & 511;
    const float* p = cw + (size_t)idx * 9;
    ushort* q = wt2 + (((size_t)(ic >> 5) * 256 + oc) * 9) * 32 + (ic & 31);
#pragma unroll
    for (int kk = 0; kk < 9; kk++)
        q[kk * 32] = f2bf(p[kk]);
}

// ---------------------------------------------------------------------------
// MFMA implicit-GEMM conv, round-10: 64oc x 64px wave tile (4 A-frags, 16
// acc -> 16 MFMAs per 4 LDS b128 reads, halving LDS-read pipe load), in-block
// split-K (waves 0-1: icc 0-7, waves 2-3: icc 8-15), and permuted-LINEAR LDS
// chunk layout [r][j][px] so every B read is 16 consecutive 16B chunks per
// quarter-wave (canonical conflict-free ds_read_b128 pattern).
__global__ __launch_bounds__(256, 2) void k_conv_mfma(
    const ushort* __restrict__ xinp,  // [4][66][66][512] bf16, border-zeroed
    const ushort* __restrict__ wt2,   // [16][256][9][32] bf16
    const float* __restrict__ cb,
    float* __restrict__ out) {
    int t    = threadIdx.x;
    int lane = t & 63;
    int wid  = t >> 6;                // 4 waves
    int half = wid >> 1;              // 0: iccs 0..7, 1: iccs 8..15
    int thh  = t & 127;               // thread id within half (2 waves = 128)
    int y0  = blockIdx.x;
    int n   = blockIdx.y;
    int och = blockIdx.z;
    int ocw = och * 128 + (wid & 1) * 64;   // wave's 64-oc base
    int l15 = lane & 15, lq = lane >> 4;

    // chunk layout: chunk = (r*4 + j)*66 + px, 16B per chunk; 792 chunks/buf
    __shared__ ushort lds[2][2][792 * 8];   // [half][buf] 50,688 B total

    f32x4 acc[4][4];
#pragma unroll
    for (int m = 0; m < 4; m++)
#pragma unroll
        for (int xs = 0; xs < 4; xs++) acc[m][xs] = (f32x4){0.f, 0.f, 0.f, 0.f};

    // staging: 792 chunks per half-buffer, 128 threads -> 7 slots (last partial)
    int goff[7]; int loff[7]; bool act[7];
#pragma unroll
    for (int k2 = 0; k2 < 7; k2++) {
        int s = thh + 128 * k2;
        act[k2] = (s < 792);
        int ss = act[k2] ? s : 0;
        int r = ss / 264, rem = ss % 264, px = rem >> 2, j = rem & 3;
        goff[k2] = ((n * 66 + y0 + r) * 66 + px) * 512 + j * 8;   // global ushort off (minus icc*32)
        loff[k2] = ((r * 4 + j) * 66 + px) << 3;                  // LDS ushort off (chunk*8)
    }
    short8 g[7];
    int icb = half * 8;

#define STAGE_LOAD(ICC)                                                        \
    {                                                                          \
        int ico_ = (ICC) * 32;                                                 \
        _Pragma("unroll")                                                      \
        for (int k2 = 0; k2 < 7; k2++)                                         \
            if (act[k2]) g[k2] = *(const short8*)(xinp + goff[k2] + ico_);     \
    }

#define STAGE_WRITE(BUF)                                                       \
    {                                                                          \
        ushort* lb = &lds[half][BUF][0];                                       \
        _Pragma("unroll")                                                      \
        for (int k2 = 0; k2 < 7; k2++)                                         \
            if (act[k2]) *(short8*)&lb[loff[k2]] = g[k2];                      \
    }

    STAGE_LOAD(icb);
    STAGE_WRITE(0);
    __syncthreads();

    int cur = 0;
    for (int it = 0; it < 8; it++) {
        int icc = icb + it;
        if (it < 7) STAGE_LOAD(icc + 1);
        const ushort* lp = &lds[half][cur][0];
        const ushort* am = wt2 + (((size_t)(icc * 256 + ocw + l15)) * 9) * 32 + lq * 8;
        short8 aC[4];
#pragma unroll
        for (int m = 0; m < 4; m++) aC[m] = *(const short8*)(am + m * 4608);
#pragma unroll
        for (int kk = 0; kk < 9; kk++) {
            short8 aN[4];
            if (kk < 8) {
#pragma unroll
                for (int m = 0; m < 4; m++)
                    aN[m] = *(const short8*)(am + m * 4608 + (kk + 1) * 32);
            }
            int ky = kk / 3, kx = kk % 3;
            const ushort* lrow = lp + (((ky * 4 + lq) * 66 + kx + l15) << 3);
            short8 b0 = *(const short8*)(lrow);
            short8 b1 = *(const short8*)(lrow + 128);
            short8 b2 = *(const short8*)(lrow + 256);
            short8 b3 = *(const short8*)(lrow + 384);
#pragma unroll
            for (int m = 0; m < 4; m++) {
                acc[m][0] = __builtin_amdgcn_mfma_f32_16x16x32_bf16(aC[m], b0, acc[m][0], 0, 0, 0);
                acc[m][1] = __builtin_amdgcn_mfma_f32_16x16x32_bf16(aC[m], b1, acc[m][1], 0, 0, 0);
                acc[m][2] = __builtin_amdgcn_mfma_f32_16x16x32_bf16(aC[m], b2, acc[m][2], 0, 0, 0);
                acc[m][3] = __builtin_amdgcn_mfma_f32_16x16x32_bf16(aC[m], b3, acc[m][3], 0, 0, 0);
            }
            if (kk < 8) {
#pragma unroll
                for (int m = 0; m < 4; m++) aC[m] = aN[m];
            }
        }
        if (it < 7) {
            STAGE_WRITE(cur ^ 1);
            __syncthreads();
            cur ^= 1;
        }
    }

    // cross-half reduction: waves 2,3 push acc through LDS (f32x4,
    // lane-consecutive), waves 0,1 add + write out.
    f32x4* red = (f32x4*)&lds[0][0][0];   // 2*16*64*16B = 32,768 B (reuse)
    int widl = wid & 1;
    __syncthreads();
    if (half == 1) {
#pragma unroll
        for (int m = 0; m < 4; m++)
#pragma unroll
            for (int xs = 0; xs < 4; xs++)
                red[(widl * 16 + m * 4 + xs) * 64 + lane] = acc[m][xs];
    }
    __syncthreads();
    if (half == 0) {
#pragma unroll
        for (int m = 0; m < 4; m++) {
#pragma unroll
            for (int xs = 0; xs < 4; xs++)
                acc[m][xs] += red[(widl * 16 + m * 4 + xs) * 64 + lane];
#pragma unroll
            for (int r = 0; r < 4; r++) {
                int oc = ocw + m * 16 + lq * 4 + r;
                float bias = cb[oc];
                float* op = out + ((size_t)(n * 256 + oc)) * HW + y0 * 64 + l15;
#pragma unroll
                for (int xs = 0; xs < 4; xs++)
                    op[xs * 16] = acc[m][xs][r] + bias;
            }
        }
    }
#undef STAGE_LOAD
#undef STAGE_WRITE
}

// ---------------------------------------------------------------------------
extern "C" void kernel_launch(void* const* d_in, const int* in_sizes, int n_in,
                              void* d_out, int out_size, void* d_ws, size_t ws_size,
                              hipStream_t stream) {
    const float* feats  = (const float*)d_in[0];
    const float* Kten   = (const float*)d_in[1];
    const float* Qten   = (const float*)d_in[2];
    const float* w_gap  = (const float*)d_in[3];
    const float* w_gapr = (const float*)d_in[4];
    const float* conv_w = (const float*)d_in[5];
    const float* conv_b = (const float*)d_in[6];
    const int*   label  = (const int*)d_in[7];
    float* ob           = (float*)d_out;

    float* ws = (float*)d_ws;
    float*    mask    = ws;                         // 16384
    unsigned* mmax    = (unsigned*)(ws + 16384);    // 4
    float*    S_f     = ws + 16384 + 4;             // 1024
    float*    S_r     = S_f + 1024;                 // 1024
    float*    att_inf = S_r + 1024;                 // 25*4*16384 = 1,638,400
    float*    Wpl     = att_inf + 1638400;          // 4*4*4096 = 65,536
    float*    att_dif = Wpl + 65536;                // 589,824
    ushort*   xinp    = (ushort*)(att_dif + 589824); // 8,921,088 ushorts
    ushort*   wt2     = xinp + 8921088;              // 1,179,648 ushorts

    const int NXT = N_IMG * C_CH * HW;              // 4,194,304

    // only the halo border needs zeroing; interior rewritten by k_prep_fused
    k_zero_border<<<N_IMG * 260, 256, 0, stream>>>(xinp);

    k_init<<<1, 64, 0, stream>>>(mmax);
    k_mask_m<<<N_IMG * H_DIM, 256, 0, stream>>>(feats, w_gap, label, mask, mmax);
    k_mask_norm<<<64, 256, 0, stream>>>(mask, mmax);

    k_plane_sum<<<N_IMG * C_CH, 256, 0, stream>>>(feats, S_f);
    k_pred<<<1, 128, 0, stream>>>(S_f, w_gap, ob + NXT);

    // infusion(feats, Q, K): scores -> scatter W -> weighted plane sum (GAP swap)
    k_att_inf<<<N_IMG * H_DIM, 1024, 0, stream>>>(Qten, Kten, att_inf);
    k_scatter_w<<<N_IMG * H_DIM, 256, 0, stream>>>(att_inf, Wpl);
    k_wsum<<<N_IMG * C_CH, 256, 0, stream>>>(feats, Wpl, S_r);
    k_pred<<<1, 128, 0, stream>>>(S_r, w_gapr, ob + NXT + N_IMG * NCLASS);

    // diffusion(feats, K, Q): patches from K, center from Q
    k_att_dif<<<N_IMG * H_DIM, 1024, 0, stream>>>(Kten, Qten, mask, att_dif);

    k_prep_w<<<512, 256, 0, stream>>>(conv_w, wt2);
    k_prep_fused<<<dim3(64, 4, 2), 256, 0, stream>>>(feats, mask, att_dif, xinp);

    k_conv_mfma<<<dim3(64, 4, 2), 256, 0, stream>>>(xinp, wt2, conv_b, ob);
}

// Round 3
// 285.151 us; speedup vs baseline: 1.0227x; 1.0227x over previous
//
#include <hip/hip_runtime.h>
#include <hip/hip_bf16.h>

#define N_IMG 4
#define C_CH 256
#define H_DIM 64
#define W_DIM 64
#define HW 4096
#define NCLASS 20
#define NHEADS 4
#define HD 64   // channels per head

typedef __attribute__((ext_vector_type(8))) short short8;
typedef __attribute__((ext_vector_type(4))) float f32x4;
typedef __attribute__((address_space(3))) ushort lds_u16;
typedef const __attribute__((address_space(1))) ushort glob_u16;

__device__ __forceinline__ ushort f2bf(float f) {
    unsigned u = __float_as_uint(f);
    u += 0x7FFFu + ((u >> 16) & 1u);   // RNE
    return (ushort)(u >> 16);
}

// ---------------------------------------------------------------------------
__global__ void k_init(unsigned* mmax) {
    if (threadIdx.x < N_IMG) mmax[threadIdx.x] = 0u;
}

// mask pre-normalization + per-image max; 256 threads: 4 c-chunks x 64 w
__global__ __launch_bounds__(256) void k_mask_m(const float* __restrict__ feats,
                         const float* __restrict__ wgap,
                         const int* __restrict__ label,
                         float* __restrict__ mask, unsigned* __restrict__ mmax) {
    int b = blockIdx.x;            // N*H = 256
    int n = b >> 6, h = b & 63;
    int t = threadIdx.x;
    int w = t & 63, cq = t >> 6;
    __shared__ float wrow[C_CH];
    __shared__ float part[4][64];
    int lab = label[n];
    wrow[t] = wgap[lab * C_CH + t];
    __syncthreads();
    const float* fp = feats + ((size_t)(n * C_CH + cq * 64)) * HW + h * W_DIM + w;
    float acc = 0.f;
    for (int c = 0; c < 64; c++) acc += fp[(size_t)c * HW] * wrow[cq * 64 + c];
    part[cq][w] = acc;
    __syncthreads();
    if (cq == 0) {
        float m = fmaxf(part[0][w] + part[1][w] + part[2][w] + part[3][w], 0.f);
        mask[n * HW + h * W_DIM + w] = m;
        for (int off = 32; off; off >>= 1) m = fmaxf(m, __shfl_down(m, off, 64));
        if (w == 0) atomicMax(&mmax[n], __float_as_uint(m));
    }
}

__global__ void k_mask_norm(float* __restrict__ mask, const unsigned* __restrict__ mmax) {
    int i = blockIdx.x * 256 + threadIdx.x;
    if (i < N_IMG * HW) {
        int n = i / HW;
        float mx = fmaxf(__uint_as_float(mmax[n]), 1.0f);
        mask[i] = mask[i] / mx;
    }
}

// per-(n,c) plane sum for GAP on feats
__global__ void k_plane_sum(const float* __restrict__ x, float* __restrict__ S) {
    int nc = blockIdx.x;
    const float* p = x + (size_t)nc * HW;
    float s = 0.f;
    for (int i = threadIdx.x; i < HW; i += 256) s += p[i];
    __shared__ float red[4];
    for (int off = 32; off; off >>= 1) s += __shfl_down(s, off, 64);
    int wid = threadIdx.x >> 6;
    if ((threadIdx.x & 63) == 0) red[wid] = s;
    __syncthreads();
    if (threadIdx.x == 0) S[nc] = red[0] + red[1] + red[2] + red[3];
}

__global__ void k_pred(const float* __restrict__ S, const float* __restrict__ wg,
                       float* __restrict__ out) {
    int idx = threadIdx.x;
    if (idx < N_IMG * NCLASS) {
        int n = idx / NCLASS, k = idx % NCLASS;
        float s = 0.f;
        for (int c = 0; c < C_CH; c++) s += wg[k * C_CH + c] * S[n * C_CH + c];
        out[idx] = s * (1.0f / HW);
    }
}

// ---------------------------------------------------------------------------
// infusion attention scores (5x5, dil 3): 16-wave structure, writes normalized
// att to global. att[((a*25+k)*N + n)*HW + h*64 + w]
__global__ __launch_bounds__(1024) void k_att_inf(
    const float* __restrict__ patch_t,   // Q (im2col side)
    const float* __restrict__ center_t,  // K (center side)
    float* __restrict__ att) {
    int b = blockIdx.x;                 // N*H = 256
    int n = b >> 6, h = b & 63;
    int t = threadIdx.x;
    int w = t & 63;
    int a = (t >> 6) & 3;
    int cq = t >> 8;                    // channel quarter
    __shared__ float att_s[4][25][64];  // 25.6 KB
    for (int i = t; i < 4 * 25 * 64; i += 1024) ((float*)att_s)[i] = 0.f;
    __syncthreads();

    int off[25];
#pragma unroll
    for (int k = 0; k < 25; k++) {
        int y = h + (k / 5 - 2) * 3, x = w + (k % 5 - 2) * 3;
        off[k] = (y >= 0 && y < 64 && x >= 0 && x < 64) ? y * 64 + x : -1;
    }
    float s[25];
#pragma unroll
    for (int k = 0; k < 25; k++) s[k] = 0.f;
    const float* cp = center_t + ((size_t)(n * C_CH + a * HD + cq * 16)) * HW + h * W_DIM + w;
    const float* pp = patch_t + ((size_t)(n * C_CH + a * HD + cq * 16)) * HW;
    for (int c = 0; c < 16; c++) {
        float cen = cp[(size_t)c * HW];
        const float* pc = pp + (size_t)c * HW;
#pragma unroll
        for (int k = 0; k < 25; k++) {
            float pv = (off[k] >= 0) ? pc[off[k]] : 0.f;
            s[k] += pv * cen;
        }
    }
#pragma unroll
    for (int k = 0; k < 25; k++) atomicAdd(&att_s[a][k][w], s[k]);
    __syncthreads();
    if (cq == 0) {
        float v[25];
        float mx = -1e30f;
#pragma unroll
        for (int k = 0; k < 25; k++) { v[k] = att_s[a][k][w]; mx = fmaxf(mx, v[k]); }
        float sum = 0.f;
#pragma unroll
        for (int k = 0; k < 25; k++) { v[k] = __expf(v[k] - mx); sum += v[k]; }
        float inv = 1.0f / sum;
#pragma unroll
        for (int k = 0; k < 25; k++)
            att[((size_t)(a * 25 + k) * N_IMG + n) * HW + h * 64 + w] = v[k] * inv;
    }
}

// W_a[n,y,x] = sum_k att[a,k,(y-dy_k, x-dx_k)] (scatter form of the GAP sum)
__global__ __launch_bounds__(256) void k_scatter_w(const float* __restrict__ att,
                                                   float* __restrict__ W) {
    int b = blockIdx.x;   // n*64 + y
    int n = b >> 6, y = b & 63;
    int t = threadIdx.x;
    int x = t & 63, a = t >> 6;
    float s = 0.f;
#pragma unroll
    for (int k = 0; k < 25; k++) {
        int sy = y - (k / 5 - 2) * 3, sx = x - (k % 5 - 2) * 3;
        if (sy >= 0 && sy < 64 && sx >= 0 && sx < 64)
            s += att[((size_t)(a * 25 + k) * N_IMG + n) * HW + sy * 64 + sx];
    }
    W[((size_t)a * N_IMG + n) * HW + y * 64 + x] = s;
}

// S_r[n,c] = sum_px feats[n,c,px] * W[a(c),n,px]  (weighted plane sum, f32x4)
__global__ __launch_bounds__(256) void k_wsum(const float* __restrict__ V,
                                              const float* __restrict__ W,
                                              float* __restrict__ S) {
    int nc = blockIdx.x;               // n*256 + c
    int n = nc >> 8, c = nc & 255;
    int a = c >> 6;
    const f32x4* p4 = (const f32x4*)(V + (size_t)nc * HW);
    const f32x4* w4 = (const f32x4*)(W + ((size_t)a * N_IMG + n) * HW);
    f32x4 a4 = (f32x4){0.f, 0.f, 0.f, 0.f};
    for (int i = threadIdx.x; i < HW / 4; i += 256) {
        f32x4 u = p4[i], v = w4[i];
        a4 += u * v;
    }
    float s = a4[0] + a4[1] + a4[2] + a4[3];
    __shared__ float red[4];
    for (int off = 32; off; off >>= 1) s += __shfl_down(s, off, 64);
    int wid = threadIdx.x >> 6;
    if ((threadIdx.x & 63) == 0) red[wid] = s;
    __syncthreads();
    if (threadIdx.x == 0) S[nc] = red[0] + red[1] + red[2] + red[3];
}

// ---------------------------------------------------------------------------
// diffusion attention scores (3x3, dil 6), masked — 16-wave version
__global__ __launch_bounds__(1024) void k_att_dif(
    const float* __restrict__ patch_t,   // K
    const float* __restrict__ center_t,  // Q
    const float* __restrict__ mask, float* __restrict__ att) {
    int b = blockIdx.x;                 // N*H = 256
    int n = b >> 6, h = b & 63;
    int t = threadIdx.x;
    int w = t & 63;
    int a = (t >> 6) & 3;
    int cq = t >> 8;
    __shared__ float att_s[4][9][64];   // 9.2 KB
    for (int i = t; i < 4 * 9 * 64; i += 1024) ((float*)att_s)[i] = 0.f;
    __syncthreads();

    int off[9];
#pragma unroll
    for (int k = 0; k < 9; k++) {
        int y = h + (k / 3 - 1) * 6, x = w + (k % 3 - 1) * 6;
        off[k] = (y >= 0 && y < 64 && x >= 0 && x < 64) ? y * 64 + x : -1;
    }
    float s[9];
#pragma unroll
    for (int k = 0; k < 9; k++) s[k] = 0.f;
    const float* cp = center_t + ((size_t)(n * C_CH + a * HD + cq * 16)) * HW + h * W_DIM + w;
    const float* pp = patch_t + ((size_t)(n * C_CH + a * HD + cq * 16)) * HW;
    for (int c = 0; c < 16; c++) {
        float cen = cp[(size_t)c * HW];
        const float* pc = pp + (size_t)c * HW;
#pragma unroll
        for (int k = 0; k < 9; k++) {
            float pv = (off[k] >= 0) ? pc[off[k]] : 0.f;
            s[k] += pv * cen;
        }
    }
#pragma unroll
    for (int k = 0; k < 9; k++) atomicAdd(&att_s[a][k][w], s[k]);
    __syncthreads();
    if (cq == 0) {
        float v[9];
        float mx = -1e30f;
#pragma unroll
        for (int k = 0; k < 9; k++) { v[k] = att_s[a][k][w]; mx = fmaxf(mx, v[k]); }
        float sum = 0.f;
#pragma unroll
        for (int k = 0; k < 9; k++) { v[k] = __expf(v[k] - mx); sum += v[k]; }
        float mm = mask[n * HW + h * W_DIM + w] / sum;
#pragma unroll
        for (int k = 0; k < 9; k++)
            att[((size_t)(a * 9 + k) * N_IMG + n) * HW + h * W_DIM + w] = v[k] * mm;
    }
}

// ---------------------------------------------------------------------------
// Zero only the halo border of xinp [4][66][66][512] (interior is fully
// rewritten by k_prep_fused every launch). 260 segments of 512 ushorts per n.
__global__ __launch_bounds__(256) void k_zero_border(ushort* __restrict__ xinp) {
    int b = blockIdx.x;            // n*260 + seg
    int n = b / 260, seg = b % 260;
    size_t base;
    if (seg < 66)       base = ((size_t)(n * 66 + 0) * 66 + seg) * 512;
    else if (seg < 132) base = ((size_t)(n * 66 + 65) * 66 + (seg - 66)) * 512;
    else {
        int c = seg - 132;
        int r = 1 + (c >> 1), x = (c & 1) ? 65 : 0;
        base = ((size_t)(n * 66 + r) * 66 + x) * 512;
    }
    ((unsigned*)(xinp + base))[threadIdx.x] = 0u;   // 256 x 4B = 1024B = 512 ushorts
}

// ---------------------------------------------------------------------------
// FUSED conv-input prep: ic<256 -> feats*mask; ic>=256 -> diffusion gather,
// both packed to bf16 padded-NHWC xinp[4][66][66][512]. One block = (y, n, x-half).
__global__ __launch_bounds__(256) void k_prep_fused(
    const float* __restrict__ feats, const float* __restrict__ mask,
    const float* __restrict__ att, ushort* __restrict__ xinp) {
    int y = blockIdx.x, n = blockIdx.y, xh = blockIdx.z;
    int t = threadIdx.x;
    int xl = t & 31, cg = t >> 5;     // 8 c-groups
    int x = xh * 32 + xl;
    __shared__ ushort sx2[32][520];
    __shared__ float att_s[4][9][64];
    for (int idx = t; idx < 4 * 9 * 64; idx += 256) {
        int a = idx / 576, rem = idx % 576, k = rem >> 6, w = rem & 63;
        int sy = y - (k / 3 - 1) * 6;
        att_s[a][k][w] = (sy >= 0 && sy < 64)
            ? att[((size_t)(a * 9 + k) * N_IMG + n) * HW + sy * 64 + w] : 0.f;
    }
    float mval = mask[n * HW + y * 64 + x];
    __syncthreads();
    int sxo[9]; bool sxv[9];
#pragma unroll
    for (int k = 0; k < 9; k++) {
        int sy = y - (k / 3 - 1) * 6, sx = x - (k % 3 - 1) * 6;
        sxo[k] = sy * 64 + sx;
        sxv[k] = (sy >= 0 && sy < 64 && sx >= 0 && sx < 64);
    }
    for (int c8 = 0; c8 < 64; c8++) {
        int c = c8 * 8 + cg;
        float v;
        if (c < 256) {
            v = feats[((size_t)(n * C_CH + c)) * HW + y * 64 + x] * mval;
        } else {
            int cd = c - 256, a = cd >> 6;
            const float* vp = feats + ((size_t)(n * C_CH + cd)) * HW;
            v = 0.f;
#pragma unroll
            for (int k = 0; k < 9; k++) {
                if (sxv[k]) v += vp[sxo[k]] * att_s[a][k][(x - (k % 3 - 1) * 6)];
            }
        }
        sx2[xl][c] = f2bf(v);
    }
    __syncthreads();
    for (int xp = 0; xp < 32; xp++) {
        unsigned lo = sx2[xp][2 * t], hi = sx2[xp][2 * t + 1];
        unsigned* dst = (unsigned*)(xinp + ((size_t)(n * 66 + y + 1) * 66 + xh * 32 + xp + 1) * 512);
        dst[t] = lo | (hi << 16);
    }
}

// prep: conv_w [256][512][3][3] f32 -> wt2[16][256][9][32] bf16 (tap-contiguous per oc)
__global__ __launch_bounds__(256) void k_prep_w(const float* __restrict__ cw,
                                                ushort* __restrict__ wt2) {
    int idx = blockIdx.x * 256 + threadIdx.x;   // oc*512+ic
    int oc = idx >> 9, ic = idx & 511;
    const float* p = cw + (size_t)idx * 9;
    ushort* q = wt2 + (((size_t)(ic >> 5) * 256 + oc) * 9) * 32 + (ic & 31);
#pragma unroll
    for (int kk = 0; kk < 9; kk++)
        q[kk * 32] = f2bf(p[kk]);
}

// ---------------------------------------------------------------------------
// MFMA implicit-GEMM conv, round-11: 8-wave blocks split (oc-half x icc-half x
// tap-half) -> 4096 waves = 16 waves/CU; global_load_lds async staging with
// source-side permutation (LDS dest linear, chunk = (r*4+j)*66+px); template-
// unrolled tap loops with depth-1 cross-icc A prefetch; 4-phase LDS reduce.
template<int TAP0, int NT>
__device__ __forceinline__ void conv_mainloop(
    glob_u16* gx, lds_u16* lb0, lds_u16* lb1,
    const ushort* lp0, const ushort* lp1,
    unsigned gof0, unsigned gof1, unsigned gof2, unsigned gof3,
    int thg, int icb, const ushort* amb_in,
    int lq, int l15, f32x4 (&acc)[4][4]) {

    const ushort* amb = amb_in;

    auto stage = [&](int icc, lds_u16* lb) {
        unsigned o = (unsigned)icc * 32u;
        __builtin_amdgcn_global_load_lds(
            (const __attribute__((address_space(1))) void*)(gx + (gof0 + o)),
            (__attribute__((address_space(3))) void*)(lb + thg * 8), 16, 0, 0);
        __builtin_amdgcn_global_load_lds(
            (const __attribute__((address_space(1))) void*)(gx + (gof1 + o)),
            (__attribute__((address_space(3))) void*)(lb + (thg + 256) * 8), 16, 0, 0);
        __builtin_amdgcn_global_load_lds(
            (const __attribute__((address_space(1))) void*)(gx + (gof2 + o)),
            (__attribute__((address_space(3))) void*)(lb + (thg + 512) * 8), 16, 0, 0);
        __builtin_amdgcn_global_load_lds(
            (const __attribute__((address_space(1))) void*)(gx + (gof3 + o)),
            (__attribute__((address_space(3))) void*)(lb + (thg + 768) * 8), 16, 0, 0);
    };

    stage(icb, lb0);
    __syncthreads();

    short8 aC0 = *(const short8*)(amb + TAP0 * 32);
    short8 aC1 = *(const short8*)(amb + TAP0 * 32 + 4608);
    short8 aC2 = *(const short8*)(amb + TAP0 * 32 + 9216);
    short8 aC3 = *(const short8*)(amb + TAP0 * 32 + 13824);

    auto compute = [&](const ushort* lp, size_t nxt) {
        const ushort* ambn = amb + nxt;
#pragma unroll
        for (int tp = TAP0; tp < TAP0 + NT; ++tp) {
            const ushort* an = (tp + 1 < TAP0 + NT) ? (amb + (tp + 1) * 32)
                                                    : (ambn + TAP0 * 32);
            short8 aN0 = *(const short8*)(an);
            short8 aN1 = *(const short8*)(an + 4608);
            short8 aN2 = *(const short8*)(an + 9216);
            short8 aN3 = *(const short8*)(an + 13824);
            const ushort* lrow = lp + ((((tp / 3) * 4 + lq) * 66 + (tp % 3) + l15) << 3);
            short8 b0 = *(const short8*)(lrow);
            short8 b1 = *(const short8*)(lrow + 128);
            acc[0][0] = __builtin_amdgcn_mfma_f32_16x16x32_bf16(aC0, b0, acc[0][0], 0, 0, 0);
            acc[1][0] = __builtin_amdgcn_mfma_f32_16x16x32_bf16(aC1, b0, acc[1][0], 0, 0, 0);
            acc[2][0] = __builtin_amdgcn_mfma_f32_16x16x32_bf16(aC2, b0, acc[2][0], 0, 0, 0);
            acc[3][0] = __builtin_amdgcn_mfma_f32_16x16x32_bf16(aC3, b0, acc[3][0], 0, 0, 0);
            acc[0][1] = __builtin_amdgcn_mfma_f32_16x16x32_bf16(aC0, b1, acc[0][1], 0, 0, 0);
            acc[1][1] = __builtin_amdgcn_mfma_f32_16x16x32_bf16(aC1, b1, acc[1][1], 0, 0, 0);
            acc[2][1] = __builtin_amdgcn_mfma_f32_16x16x32_bf16(aC2, b1, acc[2][1], 0, 0, 0);
            acc[3][1] = __builtin_amdgcn_mfma_f32_16x16x32_bf16(aC3, b1, acc[3][1], 0, 0, 0);
            short8 b2 = *(const short8*)(lrow + 256);
            short8 b3 = *(const short8*)(lrow + 384);
            acc[0][2] = __builtin_amdgcn_mfma_f32_16x16x32_bf16(aC0, b2, acc[0][2], 0, 0, 0);
            acc[1][2] = __builtin_amdgcn_mfma_f32_16x16x32_bf16(aC1, b2, acc[1][2], 0, 0, 0);
            acc[2][2] = __builtin_amdgcn_mfma_f32_16x16x32_bf16(aC2, b2, acc[2][2], 0, 0, 0);
            acc[3][2] = __builtin_amdgcn_mfma_f32_16x16x32_bf16(aC3, b2, acc[3][2], 0, 0, 0);
            acc[0][3] = __builtin_amdgcn_mfma_f32_16x16x32_bf16(aC0, b3, acc[0][3], 0, 0, 0);
            acc[1][3] = __builtin_amdgcn_mfma_f32_16x16x32_bf16(aC1, b3, acc[1][3], 0, 0, 0);
            acc[2][3] = __builtin_amdgcn_mfma_f32_16x16x32_bf16(aC2, b3, acc[2][3], 0, 0, 0);
            acc[3][3] = __builtin_amdgcn_mfma_f32_16x16x32_bf16(aC3, b3, acc[3][3], 0, 0, 0);
            aC0 = aN0; aC1 = aN1; aC2 = aN2; aC3 = aN3;
        }
        amb = ambn;
    };

    for (int d = 0; d < 4; ++d) {
        int itA = 2 * d;
        // phase A: compute buf0, stage buf1 with icc icb+itA+1 (itA <= 6)
        stage(icb + itA + 1, lb1);
        compute(lp0, 73728);
        __syncthreads();
        // phase B: compute buf1, stage buf0 with icc icb+itA+2 (if exists)
        if (d < 3) stage(icb + itA + 2, lb0);
        compute(lp1, (d < 3) ? (size_t)73728 : (size_t)0);
        __syncthreads();
    }
}

__global__ __launch_bounds__(512, 4) void k_conv_mfma(
    const ushort* __restrict__ xinp,  // [4][66][66][512] bf16, border-zeroed
    const ushort* __restrict__ wt2,   // [16][256][9][32] bf16
    const float* __restrict__ cb,
    float* __restrict__ out) {
    int t    = threadIdx.x;
    int lane = t & 63;
    int wid  = t >> 6;                 // 0..7
    int ocp  = wid & 1;                // oc half (64 oc each)
    int th   = (wid >> 1) & 1;         // tap half (taps 0-4 / 5-8)
    int ih   = wid >> 2;               // icc half (0-7 / 8-15)
    int thg  = t & 255;                // thread within icc-half group
    int y0  = blockIdx.x;
    int n   = blockIdx.y;
    int och = blockIdx.z;
    int ocw = och * 128 + ocp * 64;
    int l15 = lane & 15, lq = lane >> 4;
    int icb = ih * 8;

    // chunk layout: chunk = (r*4 + j)*66 + px (792 used, padded to 1024)
    __shared__ __align__(16) ushort lds[2][2][8192];   // [ih][buf] 64 KB

    f32x4 acc[4][4];
#pragma unroll
    for (int m = 0; m < 4; m++)
#pragma unroll
        for (int xs = 0; xs < 4; xs++) acc[m][xs] = (f32x4){0.f, 0.f, 0.f, 0.f};

    // source-side permutation: LDS chunk s <- global (r=q>>2, px, j=q&3)
    unsigned gof[4];
#pragma unroll
    for (int k2 = 0; k2 < 4; ++k2) {
        int s = thg + 256 * k2;
        int ss = (s < 792) ? s : 0;    // pad slots load chunk 0 (land in LDS pad)
        int q = ss / 66, px = ss % 66;
        int r = q >> 2, j = q & 3;
        gof[k2] = ((unsigned)((n * 66 + y0 + r) * 66 + px) << 9) + (unsigned)(j * 8);
    }

    glob_u16* gx = (glob_u16*)xinp;
    lds_u16* lb0 = (lds_u16*)&lds[ih][0][0];
    lds_u16* lb1 = (lds_u16*)&lds[ih][1][0];
    const ushort* lp0 = &lds[ih][0][0];
    const ushort* lp1 = &lds[ih][1][0];
    const ushort* amb = wt2 + ((size_t)(icb * 256 + ocw + l15) * 9) * 32 + lq * 8;

    if (th == 0)
        conv_mainloop<0, 5>(gx, lb0, lb1, lp0, lp1, gof[0], gof[1], gof[2], gof[3],
                            thg, icb, amb, lq, l15, acc);
    else
        conv_mainloop<5, 4>(gx, lb0, lb1, lp0, lp1, gof[0], gof[1], gof[2], gof[3],
                            thg, icb, amb, lq, l15, acc);

    // 4-way partial reduce (icc-half x tap-half), phased per m through LDS
    f32x4* redv = (f32x4*)&lds[0][0][0];   // per phase: 6 waves x 4 x 64 = 24,576 B
    int wix = ih * 2 + th;                 // 0..3; wix==0 waves hold the result
#pragma unroll
    for (int m = 0; m < 4; ++m) {
        if (wix != 0) {
#pragma unroll
            for (int xs = 0; xs < 4; ++xs)
                redv[(((wix - 1) * 2 + ocp) * 4 + xs) * 64 + lane] = acc[m][xs];
        }
        __syncthreads();
        if (wix == 0) {
#pragma unroll
            for (int w6 = 0; w6 < 3; ++w6)
#pragma unroll
                for (int xs = 0; xs < 4; ++xs)
                    acc[m][xs] += redv[((w6 * 2 + ocp) * 4 + xs) * 64 + lane];
        }
        __syncthreads();
    }

    if (wix == 0) {
#pragma unroll
        for (int m = 0; m < 4; ++m) {
#pragma unroll
            for (int r = 0; r < 4; ++r) {
                int oc = ocw + m * 16 + lq * 4 + r;
                float bias = cb[oc];
                float* op = out + ((size_t)(n * 256 + oc)) * HW + y0 * 64 + l15;
#pragma unroll
                for (int xs = 0; xs < 4; ++xs)
                    op[xs * 16] = acc[m][xs][r] + bias;
            }
        }
    }
}

// ---------------------------------------------------------------------------
extern "C" void kernel_launch(void* const* d_in, const int* in_sizes, int n_in,
                              void* d_out, int out_size, void* d_ws, size_t ws_size,
                              hipStream_t stream) {
    const float* feats  = (const float*)d_in[0];
    const float* Kten   = (const float*)d_in[1];
    const float* Qten   = (const float*)d_in[2];
    const float* w_gap  = (const float*)d_in[3];
    const float* w_gapr = (const float*)d_in[4];
    const float* conv_w = (const float*)d_in[5];
    const float* conv_b = (const float*)d_in[6];
    const int*   label  = (const int*)d_in[7];
    float* ob           = (float*)d_out;

    float* ws = (float*)d_ws;
    float*    mask    = ws;                         // 16384
    unsigned* mmax    = (unsigned*)(ws + 16384);    // 4
    float*    S_f     = ws + 16384 + 4;             // 1024
    float*    S_r     = S_f + 1024;                 // 1024
    float*    att_inf = S_r + 1024;                 // 25*4*16384 = 1,638,400
    float*    Wpl     = att_inf + 1638400;          // 4*4*4096 = 65,536
    float*    att_dif = Wpl + 65536;                // 589,824
    ushort*   xinp    = (ushort*)(att_dif + 589824); // 8,921,088 ushorts
    ushort*   wt2     = xinp + 8921088;              // 1,179,648 ushorts

    const int NXT = N_IMG * C_CH * HW;              // 4,194,304

    // only the halo border needs zeroing; interior rewritten by k_prep_fused
    k_zero_border<<<N_IMG * 260, 256, 0, stream>>>(xinp);

    k_init<<<1, 64, 0, stream>>>(mmax);
    k_mask_m<<<N_IMG * H_DIM, 256, 0, stream>>>(feats, w_gap, label, mask, mmax);
    k_mask_norm<<<64, 256, 0, stream>>>(mask, mmax);

    k_plane_sum<<<N_IMG * C_CH, 256, 0, stream>>>(feats, S_f);
    k_pred<<<1, 128, 0, stream>>>(S_f, w_gap, ob + NXT);

    // infusion(feats, Q, K): scores -> scatter W -> weighted plane sum (GAP swap)
    k_att_inf<<<N_IMG * H_DIM, 1024, 0, stream>>>(Qten, Kten, att_inf);
    k_scatter_w<<<N_IMG * H_DIM, 256, 0, stream>>>(att_inf, Wpl);
    k_wsum<<<N_IMG * C_CH, 256, 0, stream>>>(feats, Wpl, S_r);
    k_pred<<<1, 128, 0, stream>>>(S_r, w_gapr, ob + NXT + N_IMG * NCLASS);

    // diffusion(feats, K, Q): patches from K, center from Q
    k_att_dif<<<N_IMG * H_DIM, 1024, 0, stream>>>(Kten, Qten, mask, att_dif);

    k_prep_w<<<512, 256, 0, stream>>>(conv_w, wt2);
    k_prep_fused<<<dim3(64, 4, 2), 256, 0, stream>>>(feats, mask, att_dif, xinp);

    k_conv_mfma<<<dim3(64, 4, 2), 512, 0, stream>>>(xinp, wt2, conv_b, ob);
}

// Round 4
// 239.597 us; speedup vs baseline: 1.2172x; 1.1901x over previous
//
#include <hip/hip_runtime.h>
#include <hip/hip_bf16.h>

#define N_IMG 4
#define C_CH 256
#define H_DIM 64
#define W_DIM 64
#define HW 4096
#define NCLASS 20
#define NHEADS 4
#define HD 64   // channels per head

typedef __attribute__((ext_vector_type(8))) short short8;
typedef __attribute__((ext_vector_type(4))) float f32x4;

__device__ __forceinline__ ushort f2bf(float f) {
    unsigned u = __float_as_uint(f);
    u += 0x7FFFu + ((u >> 16) & 1u);   // RNE
    return (ushort)(u >> 16);
}

// ---------------------------------------------------------------------------
__global__ void k_init(unsigned* mmax) {
    if (threadIdx.x < N_IMG) mmax[threadIdx.x] = 0u;
}

// mask pre-normalization + per-image max; 256 threads: 4 c-chunks x 64 w
__global__ __launch_bounds__(256) void k_mask_m(const float* __restrict__ feats,
                         const float* __restrict__ wgap,
                         const int* __restrict__ label,
                         float* __restrict__ mask, unsigned* __restrict__ mmax) {
    int b = blockIdx.x;            // N*H = 256
    int n = b >> 6, h = b & 63;
    int t = threadIdx.x;
    int w = t & 63, cq = t >> 6;
    __shared__ float wrow[C_CH];
    __shared__ float part[4][64];
    int lab = label[n];
    wrow[t] = wgap[lab * C_CH + t];
    __syncthreads();
    const float* fp = feats + ((size_t)(n * C_CH + cq * 64)) * HW + h * W_DIM + w;
    float acc = 0.f;
    for (int c = 0; c < 64; c++) acc += fp[(size_t)c * HW] * wrow[cq * 64 + c];
    part[cq][w] = acc;
    __syncthreads();
    if (cq == 0) {
        float m = fmaxf(part[0][w] + part[1][w] + part[2][w] + part[3][w], 0.f);
        mask[n * HW + h * W_DIM + w] = m;
        for (int off = 32; off; off >>= 1) m = fmaxf(m, __shfl_down(m, off, 64));
        if (w == 0) atomicMax(&mmax[n], __float_as_uint(m));
    }
}

__global__ void k_mask_norm(float* __restrict__ mask, const unsigned* __restrict__ mmax) {
    int i = blockIdx.x * 256 + threadIdx.x;
    if (i < N_IMG * HW) {
        int n = i / HW;
        float mx = fmaxf(__uint_as_float(mmax[n]), 1.0f);
        mask[i] = mask[i] / mx;
    }
}

// per-(n,c) plane sum for GAP on feats
__global__ void k_plane_sum(const float* __restrict__ x, float* __restrict__ S) {
    int nc = blockIdx.x;
    const float* p = x + (size_t)nc * HW;
    float s = 0.f;
    for (int i = threadIdx.x; i < HW; i += 256) s += p[i];
    __shared__ float red[4];
    for (int off = 32; off; off >>= 1) s += __shfl_down(s, off, 64);
    int wid = threadIdx.x >> 6;
    if ((threadIdx.x & 63) == 0) red[wid] = s;
    __syncthreads();
    if (threadIdx.x == 0) S[nc] = red[0] + red[1] + red[2] + red[3];
}

__global__ void k_pred(const float* __restrict__ S, const float* __restrict__ wg,
                       float* __restrict__ out) {
    int idx = threadIdx.x;
    if (idx < N_IMG * NCLASS) {
        int n = idx / NCLASS, k = idx % NCLASS;
        float s = 0.f;
        for (int c = 0; c < C_CH; c++) s += wg[k * C_CH + c] * S[n * C_CH + c];
        out[idx] = s * (1.0f / HW);
    }
}

// ---------------------------------------------------------------------------
// infusion attention scores (5x5, dil 3): 16-wave structure, writes normalized
// att to global. att[((a*25+k)*N + n)*HW + h*64 + w]
__global__ __launch_bounds__(1024) void k_att_inf(
    const float* __restrict__ patch_t,   // Q (im2col side)
    const float* __restrict__ center_t,  // K (center side)
    float* __restrict__ att) {
    int b = blockIdx.x;                 // N*H = 256
    int n = b >> 6, h = b & 63;
    int t = threadIdx.x;
    int w = t & 63;
    int a = (t >> 6) & 3;
    int cq = t >> 8;                    // channel quarter
    __shared__ float att_s[4][25][64];  // 25.6 KB
    for (int i = t; i < 4 * 25 * 64; i += 1024) ((float*)att_s)[i] = 0.f;
    __syncthreads();

    int off[25];
#pragma unroll
    for (int k = 0; k < 25; k++) {
        int y = h + (k / 5 - 2) * 3, x = w + (k % 5 - 2) * 3;
        off[k] = (y >= 0 && y < 64 && x >= 0 && x < 64) ? y * 64 + x : -1;
    }
    float s[25];
#pragma unroll
    for (int k = 0; k < 25; k++) s[k] = 0.f;
    const float* cp = center_t + ((size_t)(n * C_CH + a * HD + cq * 16)) * HW + h * W_DIM + w;
    const float* pp = patch_t + ((size_t)(n * C_CH + a * HD + cq * 16)) * HW;
    for (int c = 0; c < 16; c++) {
        float cen = cp[(size_t)c * HW];
        const float* pc = pp + (size_t)c * HW;
#pragma unroll
        for (int k = 0; k < 25; k++) {
            float pv = (off[k] >= 0) ? pc[off[k]] : 0.f;
            s[k] += pv * cen;
        }
    }
#pragma unroll
    for (int k = 0; k < 25; k++) atomicAdd(&att_s[a][k][w], s[k]);
    __syncthreads();
    if (cq == 0) {
        float v[25];
        float mx = -1e30f;
#pragma unroll
        for (int k = 0; k < 25; k++) { v[k] = att_s[a][k][w]; mx = fmaxf(mx, v[k]); }
        float sum = 0.f;
#pragma unroll
        for (int k = 0; k < 25; k++) { v[k] = __expf(v[k] - mx); sum += v[k]; }
        float inv = 1.0f / sum;
#pragma unroll
        for (int k = 0; k < 25; k++)
            att[((size_t)(a * 25 + k) * N_IMG + n) * HW + h * 64 + w] = v[k] * inv;
    }
}

// W_a[n,y,x] = sum_k att[a,k,(y-dy_k, x-dx_k)] (scatter form of the GAP sum)
__global__ __launch_bounds__(256) void k_scatter_w(const float* __restrict__ att,
                                                   float* __restrict__ W) {
    int b = blockIdx.x;   // n*64 + y
    int n = b >> 6, y = b & 63;
    int t = threadIdx.x;
    int x = t & 63, a = t >> 6;
    float s = 0.f;
#pragma unroll
    for (int k = 0; k < 25; k++) {
        int sy = y - (k / 5 - 2) * 3, sx = x - (k % 5 - 2) * 3;
        if (sy >= 0 && sy < 64 && sx >= 0 && sx < 64)
            s += att[((size_t)(a * 25 + k) * N_IMG + n) * HW + sy * 64 + sx];
    }
    W[((size_t)a * N_IMG + n) * HW + y * 64 + x] = s;
}

// S_r[n,c] = sum_px feats[n,c,px] * W[a(c),n,px]  (weighted plane sum, f32x4)
__global__ __launch_bounds__(256) void k_wsum(const float* __restrict__ V,
                                              const float* __restrict__ W,
                                              float* __restrict__ S) {
    int nc = blockIdx.x;               // n*256 + c
    int n = nc >> 8, c = nc & 255;
    int a = c >> 6;
    const f32x4* p4 = (const f32x4*)(V + (size_t)nc * HW);
    const f32x4* w4 = (const f32x4*)(W + ((size_t)a * N_IMG + n) * HW);
    f32x4 a4 = (f32x4){0.f, 0.f, 0.f, 0.f};
    for (int i = threadIdx.x; i < HW / 4; i += 256) {
        f32x4 u = p4[i], v = w4[i];
        a4 += u * v;
    }
    float s = a4[0] + a4[1] + a4[2] + a4[3];
    __shared__ float red[4];
    for (int off = 32; off; off >>= 1) s += __shfl_down(s, off, 64);
    int wid = threadIdx.x >> 6;
    if ((threadIdx.x & 63) == 0) red[wid] = s;
    __syncthreads();
    if (threadIdx.x == 0) S[nc] = red[0] + red[1] + red[2] + red[3];
}

// ---------------------------------------------------------------------------
// diffusion attention scores (3x3, dil 6), masked — 16-wave version
__global__ __launch_bounds__(1024) void k_att_dif(
    const float* __restrict__ patch_t,   // K
    const float* __restrict__ center_t,  // Q
    const float* __restrict__ mask, float* __restrict__ att) {
    int b = blockIdx.x;                 // N*H = 256
    int n = b >> 6, h = b & 63;
    int t = threadIdx.x;
    int w = t & 63;
    int a = (t >> 6) & 3;
    int cq = t >> 8;
    __shared__ float att_s[4][9][64];   // 9.2 KB
    for (int i = t; i < 4 * 9 * 64; i += 1024) ((float*)att_s)[i] = 0.f;
    __syncthreads();

    int off[9];
#pragma unroll
    for (int k = 0; k < 9; k++) {
        int y = h + (k / 3 - 1) * 6, x = w + (k % 3 - 1) * 6;
        off[k] = (y >= 0 && y < 64 && x >= 0 && x < 64) ? y * 64 + x : -1;
    }
    float s[9];
#pragma unroll
    for (int k = 0; k < 9; k++) s[k] = 0.f;
    const float* cp = center_t + ((size_t)(n * C_CH + a * HD + cq * 16)) * HW + h * W_DIM + w;
    const float* pp = patch_t + ((size_t)(n * C_CH + a * HD + cq * 16)) * HW;
    for (int c = 0; c < 16; c++) {
        float cen = cp[(size_t)c * HW];
        const float* pc = pp + (size_t)c * HW;
#pragma unroll
        for (int k = 0; k < 9; k++) {
            float pv = (off[k] >= 0) ? pc[off[k]] : 0.f;
            s[k] += pv * cen;
        }
    }
#pragma unroll
    for (int k = 0; k < 9; k++) atomicAdd(&att_s[a][k][w], s[k]);
    __syncthreads();
    if (cq == 0) {
        float v[9];
        float mx = -1e30f;
#pragma unroll
        for (int k = 0; k < 9; k++) { v[k] = att_s[a][k][w]; mx = fmaxf(mx, v[k]); }
        float sum = 0.f;
#pragma unroll
        for (int k = 0; k < 9; k++) { v[k] = __expf(v[k] - mx); sum += v[k]; }
        float mm = mask[n * HW + h * W_DIM + w] / sum;
#pragma unroll
        for (int k = 0; k < 9; k++)
            att[((size_t)(a * 9 + k) * N_IMG + n) * HW + h * W_DIM + w] = v[k] * mm;
    }
}

// ---------------------------------------------------------------------------
// Zero only the halo border of xinp [4][66][66][512] (interior is fully
// rewritten by k_prep_fused every launch). 260 segments of 512 ushorts per n.
__global__ __launch_bounds__(256) void k_zero_border(ushort* __restrict__ xinp) {
    int b = blockIdx.x;            // n*260 + seg
    int n = b / 260, seg = b % 260;
    size_t base;
    if (seg < 66)       base = ((size_t)(n * 66 + 0) * 66 + seg) * 512;
    else if (seg < 132) base = ((size_t)(n * 66 + 65) * 66 + (seg - 66)) * 512;
    else {
        int c = seg - 132;
        int r = 1 + (c >> 1), x = (c & 1) ? 65 : 0;
        base = ((size_t)(n * 66 + r) * 66 + x) * 512;
    }
    ((unsigned*)(xinp + base))[threadIdx.x] = 0u;   // 256 x 4B = 1024B = 512 ushorts
}

// ---------------------------------------------------------------------------
// FUSED conv-input prep: ic<256 -> feats*mask; ic>=256 -> diffusion gather,
// both packed to bf16 padded-NHWC xinp[4][66][66][512]. One block = (y, n, x-half).
__global__ __launch_bounds__(256) void k_prep_fused(
    const float* __restrict__ feats, const float* __restrict__ mask,
    const float* __restrict__ att, ushort* __restrict__ xinp) {
    int y = blockIdx.x, n = blockIdx.y, xh = blockIdx.z;
    int t = threadIdx.x;
    int xl = t & 31, cg = t >> 5;     // 8 c-groups
    int x = xh * 32 + xl;
    __shared__ ushort sx2[32][520];
    __shared__ float att_s[4][9][64];
    for (int idx = t; idx < 4 * 9 * 64; idx += 256) {
        int a = idx / 576, rem = idx % 576, k = rem >> 6, w = rem & 63;
        int sy = y - (k / 3 - 1) * 6;
        att_s[a][k][w] = (sy >= 0 && sy < 64)
            ? att[((size_t)(a * 9 + k) * N_IMG + n) * HW + sy * 64 + w] : 0.f;
    }
    float mval = mask[n * HW + y * 64 + x];
    __syncthreads();
    int sxo[9]; bool sxv[9];
#pragma unroll
    for (int k = 0; k < 9; k++) {
        int sy = y - (k / 3 - 1) * 6, sx = x - (k % 3 - 1) * 6;
        sxo[k] = sy * 64 + sx;
        sxv[k] = (sy >= 0 && sy < 64 && sx >= 0 && sx < 64);
    }
    for (int c8 = 0; c8 < 64; c8++) {
        int c = c8 * 8 + cg;
        float v;
        if (c < 256) {
            v = feats[((size_t)(n * C_CH + c)) * HW + y * 64 + x] * mval;
        } else {
            int cd = c - 256, a = cd >> 6;
            const float* vp = feats + ((size_t)(n * C_CH + cd)) * HW;
            v = 0.f;
#pragma unroll
            for (int k = 0; k < 9; k++) {
                if (sxv[k]) v += vp[sxo[k]] * att_s[a][k][(x - (k % 3 - 1) * 6)];
            }
        }
        sx2[xl][c] = f2bf(v);
    }
    __syncthreads();
    for (int xp = 0; xp < 32; xp++) {
        unsigned lo = sx2[xp][2 * t], hi = sx2[xp][2 * t + 1];
        unsigned* dst = (unsigned*)(xinp + ((size_t)(n * 66 + y + 1) * 66 + xh * 32 + xp + 1) * 512);
        dst[t] = lo | (hi << 16);
    }
}

// prep: conv_w [256][512][3][3] f32 -> wt3[icc(16)][tap(9)][lq(4)][oc(256)][8] bf16
// (COALESCED A layout: lanes l15 read 16 consecutive 16B fragments per load)
__global__ __launch_bounds__(256) void k_prep_w(const float* __restrict__ cw,
                                                ushort* __restrict__ wt3) {
    int idx = blockIdx.x * 256 + threadIdx.x;   // oc*512+ic
    int oc = idx >> 9, ic = idx & 511;
    const float* p = cw + (size_t)idx * 9;
    int icc = ic >> 5, lq = (ic & 31) >> 3, pos = ic & 7;
#pragma unroll
    for (int kk = 0; kk < 9; kk++)
        wt3[((((size_t)(icc * 9 + kk)) * 4 + lq) * 256 + oc) * 8 + pos] = f2bf(p[kk]);
}

// ---------------------------------------------------------------------------
// MFMA implicit-GEMM conv (round-12 = proven round-1 structure + coalesced A
// layout + XCD-aware block swizzle): in-block split-K (512 threads, two
// 4-wave halves on icc 0-7 / 8-15, LDS acc-reduce epilogue) + chunk-XOR
// swizzled LDS + T14 reg-staging (load-early / write-late) + depth-2 A rot.
#define LDS_PXW 32   // ushorts per px row (64B = 4 chunks; swizzle, no pad)
__global__ __launch_bounds__(512, 4) void k_conv_mfma(
    const ushort* __restrict__ xinp,  // [4][66][66][512] bf16, border-zeroed
    const ushort* __restrict__ wt3,   // [16][9][4][256][8] bf16 coalesced
    const float* __restrict__ cb,
    float* __restrict__ out) {
    int t512 = threadIdx.x;
    int half = t512 >> 8;             // 0: iccs 0..7, 1: iccs 8..15
    int th   = t512 & 255;            // thread id within half
    int lane = t512 & 63;
    int wid  = (t512 >> 6) & 3;       // wave within half
    // XCD-aware swizzle: 512 blocks, 8 XCDs, 64 consecutive work-ids per XCD.
    // work id w = (n*64 + y)*2 + och  (och innermost: both och share xinp rows
    // in the same XCD's L2)
    int bid = blockIdx.x;
    int w   = (bid & 7) * 64 + (bid >> 3);
    int och = w & 1;
    int y0  = (w >> 1) & 63;
    int n   = w >> 7;
    int ocw = och * 128 + wid * 32;
    int l15 = lane & 15, lq = lane >> 4;

    // chunk layout: chunk = (r*4 + j)*66 + px, 16B per chunk; 792 chunks/buf
    __shared__ ushort lds[2][2][792 * 8];   // [half][buf] 50,688 B total

    f32x4 acc[2][4];
#pragma unroll
    for (int m = 0; m < 2; m++)
#pragma unroll
        for (int xs = 0; xs < 4; xs++) acc[m][xs] = (f32x4){0.f, 0.f, 0.f, 0.f};

    int s0 = th, s1 = th + 256, s2 = th + 512, s3 = th + 768;
    short8 g0, g1, g2, g3;
    int icb = half * 8;

    // swizzled ushort offset for chunk (r,px,j): ((px*4+j) ^ (px&7)) stays
    // within the row-pair; constant under px -> px+16 (b1/b2/b3 reads).
#define SWZ_OFF(R, PX, J) (((((((R) * 66 + (PX)) << 2) | (J)) ^ ((PX) & 7)) << 3))

#define STAGE_LOAD(ICC)                                                              \
    {                                                                                \
        int icc_ = (ICC);                                                            \
        { int r = s0 / 264, rem = s0 % 264, px = rem >> 2, j = rem & 3;              \
          g0 = *(const short8*)(xinp + ((size_t)((n * 66 + y0 + r) * 66 + px)) * 512 \
                                 + icc_ * 32 + j * 8); }                             \
        { int r = s1 / 264, rem = s1 % 264, px = rem >> 2, j = rem & 3;              \
          g1 = *(const short8*)(xinp + ((size_t)((n * 66 + y0 + r) * 66 + px)) * 512 \
                                 + icc_ * 32 + j * 8); }                             \
        { int r = s2 / 264, rem = s2 % 264, px = rem >> 2, j = rem & 3;              \
          g2 = *(const short8*)(xinp + ((size_t)((n * 66 + y0 + r) * 66 + px)) * 512 \
                                 + icc_ * 32 + j * 8); }                             \
        if (s3 < 792) {                                                              \
          int r = s3 / 264, rem = s3 % 264, px = rem >> 2, j = rem & 3;              \
          g3 = *(const short8*)(xinp + ((size_t)((n * 66 + y0 + r) * 66 + px)) * 512 \
                                 + icc_ * 32 + j * 8); }                             \
    }

#define STAGE_WRITE(BUF)                                                             \
    {                                                                                \
        ushort* lb = &lds[half][BUF][0];                                             \
        { int r = s0 / 264, rem = s0 % 264, px = rem >> 2, j = rem & 3;              \
          *(short8*)&lb[SWZ_OFF(r, px, j)] = g0; }                                   \
        { int r = s1 / 264, rem = s1 % 264, px = rem >> 2, j = rem & 3;              \
          *(short8*)&lb[SWZ_OFF(r, px, j)] = g1; }                                   \
        { int r = s2 / 264, rem = s2 % 264, px = rem >> 2, j = rem & 3;              \
          *(short8*)&lb[SWZ_OFF(r, px, j)] = g2; }                                   \
        if (s3 < 792) {                                                              \
          int r = s3 / 264, rem = s3 % 264, px = rem >> 2, j = rem & 3;              \
          *(short8*)&lb[SWZ_OFF(r, px, j)] = g3; }                                   \
    }

    STAGE_LOAD(icb);
    STAGE_WRITE(0);
    __syncthreads();

    int cur = 0;
    for (int it = 0; it < 8; it++) {
        int icc = icb + it;
        if (it < 7) STAGE_LOAD(icc + 1);
        const ushort* lp = &lds[half][cur][0];
        // coalesced A: wt3 icc-stride 73728, tap-stride 8192, lq-stride 2048,
        // oc-stride 8 ushorts; lanes l15 are 16 consecutive 16B fragments.
        const ushort* am0 = wt3 + (size_t)icc * 73728 + lq * 2048 + (ocw + l15) * 8;
        const ushort* am1 = am0 + 128;   // +16 oc
        short8 a0c = *(const short8*)(am0);
        short8 a1c = *(const short8*)(am1);
        short8 a0n = *(const short8*)(am0 + 8192);
        short8 a1n = *(const short8*)(am1 + 8192);
#pragma unroll
        for (int kk = 0; kk < 9; kk++) {
            short8 a0nn, a1nn;
            if (kk < 7) {
                a0nn = *(const short8*)(am0 + (kk + 2) * 8192);
                a1nn = *(const short8*)(am1 + (kk + 2) * 8192);
            }
            int ky = kk / 3, kx = kk % 3;
            int kxl = kx + l15;
            const ushort* lrow = lp + SWZ_OFF(ky, kxl, lq);
            short8 b0 = *(const short8*)(lrow);
            short8 b1 = *(const short8*)(lrow + 16 * LDS_PXW);
            short8 b2 = *(const short8*)(lrow + 32 * LDS_PXW);
            short8 b3 = *(const short8*)(lrow + 48 * LDS_PXW);
            acc[0][0] = __builtin_amdgcn_mfma_f32_16x16x32_bf16(a0c, b0, acc[0][0], 0, 0, 0);
            acc[1][0] = __builtin_amdgcn_mfma_f32_16x16x32_bf16(a1c, b0, acc[1][0], 0, 0, 0);
            acc[0][1] = __builtin_amdgcn_mfma_f32_16x16x32_bf16(a0c, b1, acc[0][1], 0, 0, 0);
            acc[1][1] = __builtin_amdgcn_mfma_f32_16x16x32_bf16(a1c, b1, acc[1][1], 0, 0, 0);
            acc[0][2] = __builtin_amdgcn_mfma_f32_16x16x32_bf16(a0c, b2, acc[0][2], 0, 0, 0);
            acc[1][2] = __builtin_amdgcn_mfma_f32_16x16x32_bf16(a1c, b2, acc[1][2], 0, 0, 0);
            acc[0][3] = __builtin_amdgcn_mfma_f32_16x16x32_bf16(a0c, b3, acc[0][3], 0, 0, 0);
            acc[1][3] = __builtin_amdgcn_mfma_f32_16x16x32_bf16(a1c, b3, acc[1][3], 0, 0, 0);
            a0c = a0n; a1c = a1n; a0n = a0nn; a1n = a1nn;
        }
        if (it < 7) {
            STAGE_WRITE(cur ^ 1);
            __syncthreads();
            cur ^= 1;
        }
    }

    // cross-half reduction: half 1 pushes acc through LDS (transposed,
    // stride-1 across lanes), half 0 adds + writes out.
    float* red = (float*)&lds[0][0][0];   // 32 * 256 * 4B = 32,768 B
    __syncthreads();
    if (half == 1) {
#pragma unroll
        for (int m = 0; m < 2; m++)
#pragma unroll
            for (int xs = 0; xs < 4; xs++)
#pragma unroll
                for (int r = 0; r < 4; r++)
                    red[(((m * 4 + xs) * 4) + r) * 256 + th] = acc[m][xs][r];
    }
    __syncthreads();
    if (half == 0) {
#pragma unroll
        for (int m = 0; m < 2; m++) {
#pragma unroll
            for (int r = 0; r < 4; r++) {
                int oc = ocw + m * 16 + lq * 4 + r;
                float bias = cb[oc];
                float* op = out + ((size_t)(n * 256 + oc)) * HW + y0 * 64 + l15;
#pragma unroll
                for (int xs = 0; xs < 4; xs++)
                    op[xs * 16] = acc[m][xs][r] + red[(((m * 4 + xs) * 4) + r) * 256 + th] + bias;
            }
        }
    }
#undef STAGE_LOAD
#undef STAGE_WRITE
#undef SWZ_OFF
}

// ---------------------------------------------------------------------------
extern "C" void kernel_launch(void* const* d_in, const int* in_sizes, int n_in,
                              void* d_out, int out_size, void* d_ws, size_t ws_size,
                              hipStream_t stream) {
    const float* feats  = (const float*)d_in[0];
    const float* Kten   = (const float*)d_in[1];
    const float* Qten   = (const float*)d_in[2];
    const float* w_gap  = (const float*)d_in[3];
    const float* w_gapr = (const float*)d_in[4];
    const float* conv_w = (const float*)d_in[5];
    const float* conv_b = (const float*)d_in[6];
    const int*   label  = (const int*)d_in[7];
    float* ob           = (float*)d_out;

    float* ws = (float*)d_ws;
    float*    mask    = ws;                         // 16384
    unsigned* mmax    = (unsigned*)(ws + 16384);    // 4
    float*    S_f     = ws + 16384 + 4;             // 1024
    float*    S_r     = S_f + 1024;                 // 1024
    float*    att_inf = S_r + 1024;                 // 25*4*16384 = 1,638,400
    float*    Wpl     = att_inf + 1638400;          // 4*4*4096 = 65,536
    float*    att_dif = Wpl + 65536;                // 589,824
    ushort*   xinp    = (ushort*)(att_dif + 589824); // 8,921,088 ushorts
    ushort*   wt3     = xinp + 8921088;              // 1,179,648 ushorts

    const int NXT = N_IMG * C_CH * HW;              // 4,194,304

    // only the halo border needs zeroing; interior rewritten by k_prep_fused
    k_zero_border<<<N_IMG * 260, 256, 0, stream>>>(xinp);

    k_init<<<1, 64, 0, stream>>>(mmax);
    k_mask_m<<<N_IMG * H_DIM, 256, 0, stream>>>(feats, w_gap, label, mask, mmax);
    k_mask_norm<<<64, 256, 0, stream>>>(mask, mmax);

    k_plane_sum<<<N_IMG * C_CH, 256, 0, stream>>>(feats, S_f);
    k_pred<<<1, 128, 0, stream>>>(S_f, w_gap, ob + NXT);

    // infusion(feats, Q, K): scores -> scatter W -> weighted plane sum (GAP swap)
    k_att_inf<<<N_IMG * H_DIM, 1024, 0, stream>>>(Qten, Kten, att_inf);
    k_scatter_w<<<N_IMG * H_DIM, 256, 0, stream>>>(att_inf, Wpl);
    k_wsum<<<N_IMG * C_CH, 256, 0, stream>>>(feats, Wpl, S_r);
    k_pred<<<1, 128, 0, stream>>>(S_r, w_gapr, ob + NXT + N_IMG * NCLASS);

    // diffusion(feats, K, Q): patches from K, center from Q
    k_att_dif<<<N_IMG * H_DIM, 1024, 0, stream>>>(Kten, Qten, mask, att_dif);

    k_prep_w<<<512, 256, 0, stream>>>(conv_w, wt3);
    k_prep_fused<<<dim3(64, 4, 2), 256, 0, stream>>>(feats, mask, att_dif, xinp);

    k_conv_mfma<<<512, 512, 0, stream>>>(xinp, wt3, conv_b, ob);
}